// Round 1
// baseline (3706.661 us; speedup 1.0000x reference)
//
#include <hip/hip_runtime.h>
#include <hip/hip_bf16.h>

// Shapes (fixed): L=2048, B=8, D=1024, R=8, E=2, RD=8, H=512, NUM_STAT=3, TOPK=1
// tokens M = L*B = 16384

typedef __attribute__((ext_vector_type(4))) float f32x4;
typedef __attribute__((ext_vector_type(8))) short bf16x8;

__device__ __forceinline__ float geluf(float v) {
    return 0.5f * v * (1.0f + erff(v * 0.70710678118654752440f));
}
__device__ __forceinline__ unsigned short f2bf(float v) {
    return __builtin_bit_cast(unsigned short, __float2bfloat16(v));
}

// ---------------- prep: fold missing_embed@W1[1024:] + b1 into C[b][h]; act flags ----
__global__ void kprep(const float* __restrict__ me, const float* __restrict__ W1,
                      const float* __restrict__ b1, float* __restrict__ Cb,
                      float* __restrict__ actb) {
    int h = threadIdx.x;  // 512 threads
    for (int b = 0; b < 8; b++) {
        float s = b1[h];
        #pragma unroll
        for (int r = 0; r < 8; r++) s += me[b * 8 + r] * W1[(1024 + r) * 512 + h];
        Cb[b * 512 + h] = s;
    }
    if (h < 16) {
        int b = h >> 1, j = h & 1;
        actb[b * 2 + j] = (me[b * 8 + 1 + j] > 0.5f) ? 1.0f : 0.0f;
    }
}

// ---------------- Wout -> WoutT (bf16, [n][k]) --------------------------------------
__global__ void kwout(const float* __restrict__ Wout, unsigned short* __restrict__ WT) {
    __shared__ float s[32][33];
    const int blk = blockIdx.x;
    const int kt = blk >> 5, nt = blk & 31;
    const int r = threadIdx.x >> 3, c4 = (threadIdx.x & 7) * 4;
    f32x4 v = *(const f32x4*)(Wout + (size_t)(kt * 32 + r) * 1024 + nt * 32 + c4);
    s[r][c4 + 0] = v[0]; s[r][c4 + 1] = v[1]; s[r][c4 + 2] = v[2]; s[r][c4 + 3] = v[3];
    __syncthreads();
    // write WT[n][k] = Wout[k][n]
    const int n = r, kc = c4;
    ushort4 o;
    o.x = f2bf(s[kc + 0][n]); o.y = f2bf(s[kc + 1][n]);
    o.z = f2bf(s[kc + 2][n]); o.w = f2bf(s[kc + 3][n]);
    *(ushort4*)(WT + (size_t)(nt * 32 + n) * 1024 + kt * 32 + kc) = o;
}

// ---------------- router: pre=x@W1a+C, gelu, logits, top1, r=x@A_all, rs scaled -----
__launch_bounds__(256, 2)
__global__ void krouter(const float* __restrict__ x, const float* __restrict__ W1,
                        const float* __restrict__ A_dyn, const float* __restrict__ A_stat,
                        const float* __restrict__ W2, const float* __restrict__ b2,
                        const float* __restrict__ Cb, const float* __restrict__ actb,
                        float* __restrict__ rs_out) {
    __shared__ float ws1[32 * 512];   // W1 tile [k][512]   64 KB
    __shared__ float xs[32][36];      // x tile  [t][k]     4.6 KB
    __shared__ float as_[32 * 40];    // A tile  [k][40]    5 KB
    __shared__ float rbuf[32][40];    // r values per token 5 KB

    const int tid = threadIdx.x;
    const int tg = tid >> 5;    // 0..7, owns tokens 4tg..4tg+3
    const int cg = tid & 31;    // 0..31, owns cols {4cg+128j}
    const int m0 = blockIdx.x * 32;

    f32x4 acc[4][4];
    #pragma unroll
    for (int i = 0; i < 4; i++)
        #pragma unroll
        for (int j = 0; j < 4; j++) acc[i][j] = f32x4{0.f, 0.f, 0.f, 0.f};
    float racc[4][2] = {{0.f,0.f},{0.f,0.f},{0.f,0.f},{0.f,0.f}};

    const int xt = tid >> 3;          // staging: token row
    const int xk = (tid & 7) * 4;     // staging: k offset

    for (int k0 = 0; k0 < 1024; k0 += 32) {
        __syncthreads();
        // stage W1 tile (contiguous 64 KB of W1)
        const float* wsrc = W1 + k0 * 512;
        #pragma unroll
        for (int q = 0; q < 16; q++) {
            int flat = tid + 256 * q;
            f32x4 v = *(const f32x4*)(wsrc + flat * 4);
            *(f32x4*)&ws1[flat * 4] = v;
        }
        // stage x tile
        {
            f32x4 v = *(const f32x4*)(x + (size_t)(m0 + xt) * 1024 + k0 + xk);
            *(f32x4*)&xs[xt][xk] = v;
        }
        // stage A tile [32][40]: cols 0..15 A_dyn, 16..39 A_stat
        #pragma unroll
        for (int q = 0; q < 5; q++) {
            int f = tid + 256 * q;       // < 1280
            int d = f / 40, ii = f - d * 40;
            int mi = ii >> 3, r = ii & 7;
            const float* Ab = (mi < 2) ? (A_dyn + mi * 8192) : (A_stat + (mi - 2) * 8192);
            as_[d * 40 + ii] = Ab[(size_t)(k0 + d) * 8 + r];
        }
        __syncthreads();
        // main fp32 micro-kernel: 4 tokens x 16 cols per thread
        #pragma unroll
        for (int k4 = 0; k4 < 8; k4++) {
            f32x4 xa[4];
            #pragma unroll
            for (int i = 0; i < 4; i++) xa[i] = *(const f32x4*)&xs[4 * tg + i][k4 * 4];
            #pragma unroll
            for (int kk = 0; kk < 4; kk++) {
                const int krow = (k4 * 4 + kk) * 512;
                #pragma unroll
                for (int j = 0; j < 4; j++) {
                    f32x4 w = *(const f32x4*)&ws1[krow + 4 * cg + 128 * j];
                    #pragma unroll
                    for (int i = 0; i < 4; i++) acc[i][j] += w * xa[i][kk];
                }
            }
        }
        // r projection (40 cols, 2 per thread for cg<20)
        if (cg < 20) {
            #pragma unroll 4
            for (int kk = 0; kk < 32; kk++) {
                float a0 = as_[kk * 40 + 2 * cg];
                float a1 = as_[kk * 40 + 2 * cg + 1];
                #pragma unroll
                for (int i = 0; i < 4; i++) {
                    float xv = xs[4 * tg + i][kk];
                    racc[i][0] += xv * a0;
                    racc[i][1] += xv * a1;
                }
            }
        }
    }

    if (cg < 20) {
        #pragma unroll
        for (int i = 0; i < 4; i++) {
            rbuf[4 * tg + i][2 * cg]     = racc[i][0];
            rbuf[4 * tg + i][2 * cg + 1] = racc[i][1];
        }
    }

    // bias + exact gelu + partial logits
    float pl[4][2];
    #pragma unroll
    for (int i = 0; i < 4; i++) {
        const int t = 4 * tg + i;
        const int b = (m0 + t) & 7;
        float s0 = 0.f, s1 = 0.f;
        #pragma unroll
        for (int j = 0; j < 4; j++) {
            f32x4 c4 = *(const f32x4*)&Cb[b * 512 + 4 * cg + 128 * j];
            f32x4 v = acc[i][j] + c4;
            #pragma unroll
            for (int q = 0; q < 4; q++) {
                float hv = geluf(v[q]);
                int hc = 4 * cg + 128 * j + q;
                s0 += hv * W2[hc * 2 + 0];
                s1 += hv * W2[hc * 2 + 1];
            }
        }
        pl[i][0] = s0; pl[i][1] = s1;
    }
    // reduce over the 32 col-group lanes
    #pragma unroll
    for (int off = 16; off > 0; off >>= 1) {
        #pragma unroll
        for (int i = 0; i < 4; i++) {
            pl[i][0] += __shfl_xor(pl[i][0], off, 32);
            pl[i][1] += __shfl_xor(pl[i][1], off, 32);
        }
    }
    __syncthreads();
    if (cg == 0) {
        const float bb0 = b2[0], bb1 = b2[1];
        #pragma unroll
        for (int i = 0; i < 4; i++) {
            const int t = 4 * tg + i;
            const int tglob = m0 + t;
            const int b = tglob & 7;
            float l0 = pl[i][0] + bb0;
            float l1 = pl[i][1] + bb1;
            float topv = 1.f / (1.f + expf(-fabsf(l0 - l1)));
            float w0 = (l0 >= l1) ? topv : 0.f;
            float w1 = (l0 >= l1) ? 0.f : topv;
            float wsc[5];
            wsc[0] = w0; wsc[1] = w1; wsc[2] = 1.f;
            wsc[3] = actb[b * 2 + 0]; wsc[4] = actb[b * 2 + 1];
            float* dst = rs_out + (size_t)tglob * 40;
            #pragma unroll
            for (int mI = 0; mI < 5; mI++)
                for (int r = 0; r < 8; r++)
                    dst[mI * 8 + r] = wsc[mI] * rbuf[t][mI * 8 + r];
        }
    }
}

// ---------------- delta = rs@B_all ; z = bf16(gelu(delta)) --------------------------
__global__ void kdelta(const float* __restrict__ rs, const float* __restrict__ B_dyn,
                       const float* __restrict__ B_stat, unsigned short* __restrict__ z) {
    __shared__ float rl[16 * 40];
    const int tid = threadIdx.x;
    const int t0 = blockIdx.x * 16;
    for (int f = tid; f < 640; f += 256) rl[f] = rs[(size_t)t0 * 40 + f];
    __syncthreads();
    const int c0 = tid * 4;   // 4 cols per thread, 256*4 = 1024
    f32x4 acc[16];
    #pragma unroll
    for (int t = 0; t < 16; t++) acc[t] = f32x4{0.f, 0.f, 0.f, 0.f};
    for (int i = 0; i < 40; i++) {
        const float* Brow = (i < 16) ? (B_dyn + (size_t)i * 1024)
                                     : (B_stat + (size_t)(i - 16) * 1024);
        f32x4 b4 = *(const f32x4*)(Brow + c0);
        #pragma unroll
        for (int t = 0; t < 16; t++) acc[t] += b4 * rl[t * 40 + i];
    }
    #pragma unroll
    for (int t = 0; t < 16; t++) {
        f32x4 v = acc[t];
        ushort4 o;
        o.x = f2bf(geluf(v[0])); o.y = f2bf(geluf(v[1]));
        o.z = f2bf(geluf(v[2])); o.w = f2bf(geluf(v[3]));
        *(ushort4*)(z + (size_t)(t0 + t) * 1024 + c0) = o;
    }
}

// ---------------- out = z @ Wout + bout (bf16 MFMA, 128x128 tiles) ------------------
__launch_bounds__(256, 2)
__global__ void kgemm(const unsigned short* __restrict__ z,
                      const unsigned short* __restrict__ WT,
                      const float* __restrict__ bout, float* __restrict__ out) {
    __shared__ unsigned short lA[128 * 32];  // [row][32] bf16, slot-swizzled, 8 KB
    __shared__ unsigned short lB[128 * 32];
    const int tid = threadIdx.x;
    const int lane = tid & 63;
    const int wave = tid >> 6;
    const int m0 = (blockIdx.x >> 3) * 128;
    const int n0 = (blockIdx.x & 7) * 128;
    const int wm = wave >> 1, wn = wave & 1;

    f32x4 acc[4][4];
    #pragma unroll
    for (int i = 0; i < 4; i++)
        #pragma unroll
        for (int j = 0; j < 4; j++) acc[i][j] = f32x4{0.f, 0.f, 0.f, 0.f};

    for (int k0 = 0; k0 < 1024; k0 += 32) {
        __syncthreads();
        // stage both tiles; 16B chunk per lane; XOR-swizzle 16B slots within each 64B row
        #pragma unroll
        for (int q = 0; q < 2; q++) {
            int c = tid + 256 * q;
            int row = c >> 2, ss = c & 3;
            int sl = ss ^ ((row >> 1) & 3);
            f32x4 va = *(const f32x4*)(z + (size_t)(m0 + row) * 1024 + k0 + sl * 8);
            *(f32x4*)&lA[row * 32 + ss * 8] = va;
            f32x4 vb = *(const f32x4*)(WT + (size_t)(n0 + row) * 1024 + k0 + sl * 8);
            *(f32x4*)&lB[row * 32 + ss * 8] = vb;
        }
        __syncthreads();
        bf16x8 af[4], bfr[4];
        #pragma unroll
        for (int fi = 0; fi < 4; fi++) {
            int rA = 64 * wm + 16 * fi + (lane & 15);
            int sl = (lane >> 4) ^ ((rA >> 1) & 3);
            af[fi] = *(const bf16x8*)&lA[rA * 32 + sl * 8];
        }
        #pragma unroll
        for (int fj = 0; fj < 4; fj++) {
            int rB = 64 * wn + 16 * fj + (lane & 15);
            int sl = (lane >> 4) ^ ((rB >> 1) & 3);
            bfr[fj] = *(const bf16x8*)&lB[rB * 32 + sl * 8];
        }
        #pragma unroll
        for (int fi = 0; fi < 4; fi++)
            #pragma unroll
            for (int fj = 0; fj < 4; fj++)
                acc[fi][fj] = __builtin_amdgcn_mfma_f32_16x16x32_bf16(
                    af[fi], bfr[fj], acc[fi][fj], 0, 0, 0);
    }
    // epilogue: C/D layout col=lane&15, row=(lane>>4)*4+q  [verified mapping]
    #pragma unroll
    for (int fj = 0; fj < 4; fj++) {
        int n = n0 + 64 * wn + 16 * fj + (lane & 15);
        float bo = bout[n];
        #pragma unroll
        for (int fi = 0; fi < 4; fi++) {
            int mr = m0 + 64 * wm + 16 * fi + (lane >> 4) * 4;
            #pragma unroll
            for (int q = 0; q < 4; q++)
                out[(size_t)(mr + q) * 1024 + n] = acc[fi][fj][q] + bo;
        }
    }
}

extern "C" void kernel_launch(void* const* d_in, const int* in_sizes, int n_in,
                              void* d_out, int out_size, void* d_ws, size_t ws_size,
                              hipStream_t stream) {
    const float* x      = (const float*)d_in[0];
    const float* me     = (const float*)d_in[1];
    const float* A_dyn  = (const float*)d_in[2];
    const float* B_dyn  = (const float*)d_in[3];
    const float* W1     = (const float*)d_in[4];
    const float* b1     = (const float*)d_in[5];
    const float* W2     = (const float*)d_in[6];
    const float* b2     = (const float*)d_in[7];
    const float* A_stat = (const float*)d_in[8];
    const float* B_stat = (const float*)d_in[9];
    const float* Wout   = (const float*)d_in[10];
    const float* bout   = (const float*)d_in[11];
    float* out = (float*)d_out;

    char* ws = (char*)d_ws;
    float* Cb            = (float*)(ws);                              // 16 KB
    float* actb          = (float*)(ws + 16384);                      // 64 B
    unsigned short* WT   = (unsigned short*)(ws + 65536);             // 2 MB
    float* rs            = (float*)(ws + 65536 + 2097152);            // 2.62 MB
    unsigned short* z    = (unsigned short*)(ws + 65536 + 2097152 + 2621440);  // 32 MB

    kprep<<<1, 512, 0, stream>>>(me, W1, b1, Cb, actb);
    kwout<<<1024, 256, 0, stream>>>(Wout, WT);
    krouter<<<512, 256, 0, stream>>>(x, W1, A_dyn, A_stat, W2, b2, Cb, actb, rs);
    kdelta<<<1024, 256, 0, stream>>>(rs, B_dyn, B_stat, z);
    kgemm<<<1024, 256, 0, stream>>>(z, WT, bout, out);
}

// Round 2
// 416.762 us; speedup vs baseline: 8.8940x; 8.8940x over previous
//
#include <hip/hip_runtime.h>
#include <hip/hip_bf16.h>

// Shapes (fixed): L=2048, B=8, D=1024, R=8, E=2, RD=8, H=512, NUM_STAT=3, TOPK=1
// tokens M = L*B = 16384
//
// Pipeline:
//  kprep   : Cb[b][512] = b1 + me[b]@W1[1024:], actb flags
//  kwout   : WoutT bf16 [n][k]
//  kwsplit : WT1cat hi/lo bf16 [640][1024]  (cols 0-511 = W1^T, 512-551 = A_all^T, rest 0)
//  krouterg: split-bf16 MFMA GEMM [16384x640] = x @ [W1 | A_all]; per n-tile partial
//            logits (gelu+W2 reduce) -> plog; r-tile raw r values -> r_raw
//  kgates  : sum plog + b2 -> logits; tokens with margin < 1e-3 recomputed in exact
//            fp32 (argmax safety); write gates (w0,w1)
//  kdelta  : rs = wsc*r; delta = rs@B_all; z = bf16(gelu(delta))
//  kgemm   : out = z @ Wout + bout   (bf16 MFMA 128x128 tiles)

typedef __attribute__((ext_vector_type(4))) float f32x4;
typedef __attribute__((ext_vector_type(8))) short bf16x8;
typedef __attribute__((ext_vector_type(8))) unsigned short u16x8;

__device__ __forceinline__ float geluf(float v) {
    return 0.5f * v * (1.0f + erff(v * 0.70710678118654752440f));
}
__device__ __forceinline__ unsigned short f2bf(float v) {
    return __builtin_bit_cast(unsigned short, __float2bfloat16(v));
}
__device__ __forceinline__ float bf2f(unsigned short u) {
    unsigned int x = ((unsigned int)u) << 16;
    return __builtin_bit_cast(float, x);
}
__device__ __forceinline__ void gload16(const void* g, void* l) {
    __builtin_amdgcn_global_load_lds(
        (const __attribute__((address_space(1))) unsigned int*)g,
        (__attribute__((address_space(3))) unsigned int*)l, 16, 0, 0);
}

// ---------------- prep: fold missing_embed@W1[1024:] + b1 into Cb[b][h]; act flags --
__global__ void kprep(const float* __restrict__ me, const float* __restrict__ W1,
                      const float* __restrict__ b1, float* __restrict__ Cb,
                      float* __restrict__ actb) {
    int h = threadIdx.x;  // 512 threads
    for (int b = 0; b < 8; b++) {
        float s = b1[h];
        #pragma unroll
        for (int r = 0; r < 8; r++) s += me[b * 8 + r] * W1[(1024 + r) * 512 + h];
        Cb[b * 512 + h] = s;
    }
    if (h < 16) {
        int b = h >> 1, j = h & 1;
        actb[b * 2 + j] = (me[b * 8 + 1 + j] > 0.5f) ? 1.0f : 0.0f;
    }
}

// ---------------- Wout -> WoutT (bf16, [n][k]) --------------------------------------
__global__ void kwout(const float* __restrict__ Wout, unsigned short* __restrict__ WT) {
    __shared__ float s[32][33];
    const int blk = blockIdx.x;
    const int kt = blk >> 5, nt = blk & 31;
    const int r = threadIdx.x >> 3, c4 = (threadIdx.x & 7) * 4;
    f32x4 v = *(const f32x4*)(Wout + (size_t)(kt * 32 + r) * 1024 + nt * 32 + c4);
    s[r][c4 + 0] = v[0]; s[r][c4 + 1] = v[1]; s[r][c4 + 2] = v[2]; s[r][c4 + 3] = v[3];
    __syncthreads();
    const int n = r, kc = c4;
    ushort4 o;
    o.x = f2bf(s[kc + 0][n]); o.y = f2bf(s[kc + 1][n]);
    o.z = f2bf(s[kc + 2][n]); o.w = f2bf(s[kc + 3][n]);
    *(ushort4*)(WT + (size_t)(nt * 32 + n) * 1024 + kt * 32 + kc) = o;
}

// ---------------- build WT1cat hi/lo: [640][1024] bf16 each -------------------------
__global__ void kwsplit(const float* __restrict__ W1, const float* __restrict__ A_dyn,
                        const float* __restrict__ A_stat,
                        unsigned short* __restrict__ WThi, unsigned short* __restrict__ WTlo) {
    __shared__ float s[32][33];
    const int nt = blockIdx.x >> 5;   // 0..19
    const int kt = blockIdx.x & 31;   // 0..31
    const int r = threadIdx.x >> 3;        // 0..31 (k within tile on load; n on store)
    const int c4 = (threadIdx.x & 7) * 4;  // 0..28
    const int k = kt * 32 + r;
    if (nt < 16) {
        f32x4 v = *(const f32x4*)(W1 + (size_t)k * 512 + nt * 32 + c4);
        s[r][c4 + 0] = v[0]; s[r][c4 + 1] = v[1];
        s[r][c4 + 2] = v[2]; s[r][c4 + 3] = v[3];
    } else {
        #pragma unroll
        for (int j = 0; j < 4; j++) {
            int ng = nt * 32 + c4 + j;
            float val = 0.f;
            if (ng < 552) {
                int mi = (ng - 512) >> 3, rr = (ng - 512) & 7;
                const float* Ab = (mi < 2) ? (A_dyn + (size_t)mi * 8192)
                                           : (A_stat + (size_t)(mi - 2) * 8192);
                val = Ab[(size_t)k * 8 + rr];
            }
            s[r][c4 + j] = val;
        }
    }
    __syncthreads();
    ushort4 oh, ol;
    float f0 = s[c4 + 0][r], f1 = s[c4 + 1][r], f2 = s[c4 + 2][r], f3 = s[c4 + 3][r];
    oh.x = f2bf(f0); ol.x = f2bf(f0 - bf2f(oh.x));
    oh.y = f2bf(f1); ol.y = f2bf(f1 - bf2f(oh.y));
    oh.z = f2bf(f2); ol.z = f2bf(f2 - bf2f(oh.z));
    oh.w = f2bf(f3); ol.w = f2bf(f3 - bf2f(oh.w));
    size_t obase = (size_t)(nt * 32 + r) * 1024 + kt * 32 + c4;
    *(ushort4*)(WThi + obase) = oh;
    *(ushort4*)(WTlo + obase) = ol;
}

// ---------------- router GEMM: split-bf16 MFMA, partial logits + r ------------------
__launch_bounds__(256)
__global__ void krouterg(const float* __restrict__ x,
                         const unsigned short* __restrict__ WThi,
                         const unsigned short* __restrict__ WTlo,
                         const float* __restrict__ Cb,
                         const float* __restrict__ W2,
                         float* __restrict__ plog,
                         float* __restrict__ r_raw) {
    __shared__ unsigned short xhi[128 * 32], xlo[128 * 32];
    __shared__ unsigned short bhi_s[128 * 32], blo_s[128 * 32];
    __shared__ float plw[4][64][2];

    const int tid = threadIdx.x;
    const int lane = tid & 63;
    const int wave = tid >> 6;
    const int nt = blockIdx.x % 5;
    const int mb = blockIdx.x / 5;
    const int m0 = mb * 128, n0 = nt * 128;
    const int wm = wave >> 1, wn = wave & 1;

    f32x4 acc[4][4];
    #pragma unroll
    for (int i = 0; i < 4; i++)
        #pragma unroll
        for (int j = 0; j < 4; j++) acc[i][j] = f32x4{0.f, 0.f, 0.f, 0.f};

    // x staging: thread -> (row, 16-float chunk)
    const int sr = tid >> 1;
    const int sc = (tid & 1) * 16;
    const float* xsrc = x + (size_t)(m0 + sr) * 1024 + sc;
    const int swz = (sr >> 1) & 3;
    const int st0 = sr * 32 + (((sc >> 3) + 0) ^ swz) * 8;
    const int st1 = sr * 32 + (((sc >> 3) + 1) ^ swz) * 8;

    // B staging via global_load_lds: linear LDS dest, pre-swizzled global source
    int brow[2], bsl[2], bofs[2];
    #pragma unroll
    for (int i = 0; i < 2; i++) {
        int ldsbyte = i * 4096 + tid * 16;
        int row = ldsbyte >> 6;
        int ss = (ldsbyte >> 4) & 3;
        brow[i] = row;
        bsl[i] = ss ^ ((row >> 1) & 3);
        bofs[i] = ldsbyte >> 1;  // ushort index
    }

    // fragment LDS offsets
    int aoff[4], boff[4];
    #pragma unroll
    for (int f = 0; f < 4; f++) {
        int rA = 64 * wm + 16 * f + (lane & 15);
        aoff[f] = rA * 32 + (((lane >> 4) ^ ((rA >> 1) & 3)) * 8);
        int rB = 64 * wn + 16 * f + (lane & 15);
        boff[f] = rB * 32 + (((lane >> 4) ^ ((rB >> 1) & 3)) * 8);
    }

    for (int k0 = 0; k0 < 1024; k0 += 32) {
        __syncthreads();
        #pragma unroll
        for (int i = 0; i < 2; i++) {
            const unsigned short* g1 = WThi + (size_t)(n0 + brow[i]) * 1024 + k0 + bsl[i] * 8;
            gload16(g1, &bhi_s[bofs[i]]);
            const unsigned short* g2 = WTlo + (size_t)(n0 + brow[i]) * 1024 + k0 + bsl[i] * 8;
            gload16(g2, &blo_s[bofs[i]]);
        }
        f32x4 v0 = *(const f32x4*)(xsrc + 0);
        f32x4 v1 = *(const f32x4*)(xsrc + 4);
        f32x4 v2 = *(const f32x4*)(xsrc + 8);
        f32x4 v3 = *(const f32x4*)(xsrc + 12);
        xsrc += 32;
        u16x8 h0, l0v, h1, l1v;
        #pragma unroll
        for (int j = 0; j < 4; j++) {
            float f = v0[j]; unsigned short hs = f2bf(f);
            h0[j] = hs; l0v[j] = f2bf(f - bf2f(hs));
            f = v1[j]; hs = f2bf(f);
            h0[4 + j] = hs; l0v[4 + j] = f2bf(f - bf2f(hs));
            f = v2[j]; hs = f2bf(f);
            h1[j] = hs; l1v[j] = f2bf(f - bf2f(hs));
            f = v3[j]; hs = f2bf(f);
            h1[4 + j] = hs; l1v[4 + j] = f2bf(f - bf2f(hs));
        }
        *(u16x8*)&xhi[st0] = h0; *(u16x8*)&xlo[st0] = l0v;
        *(u16x8*)&xhi[st1] = h1; *(u16x8*)&xlo[st1] = l1v;
        __syncthreads();
        bf16x8 ah[4], al[4], bh[4], bl[4];
        #pragma unroll
        for (int f = 0; f < 4; f++) {
            ah[f] = *(const bf16x8*)&xhi[aoff[f]];
            al[f] = *(const bf16x8*)&xlo[aoff[f]];
            bh[f] = *(const bf16x8*)&bhi_s[boff[f]];
            bl[f] = *(const bf16x8*)&blo_s[boff[f]];
        }
        #pragma unroll
        for (int fi = 0; fi < 4; fi++)
            #pragma unroll
            for (int fj = 0; fj < 4; fj++) {
                acc[fi][fj] = __builtin_amdgcn_mfma_f32_16x16x32_bf16(ah[fi], bh[fj], acc[fi][fj], 0, 0, 0);
                acc[fi][fj] = __builtin_amdgcn_mfma_f32_16x16x32_bf16(ah[fi], bl[fj], acc[fi][fj], 0, 0, 0);
                acc[fi][fj] = __builtin_amdgcn_mfma_f32_16x16x32_bf16(al[fi], bh[fj], acc[fi][fj], 0, 0, 0);
            }
    }

    if (nt < 4) {
        // partial logits over this block's 128 h-cols
        #pragma unroll
        for (int fi = 0; fi < 4; fi++) {
            #pragma unroll
            for (int q = 0; q < 4; q++) {
                const int b = (((lane >> 4) * 4 + q) & 7);
                float s0 = 0.f, s1 = 0.f;
                #pragma unroll
                for (int fj = 0; fj < 4; fj++) {
                    int col = n0 + 64 * wn + 16 * fj + (lane & 15);
                    float val = acc[fi][fj][q] + Cb[b * 512 + col];
                    float hv = geluf(val);
                    s0 += hv * W2[col * 2];
                    s1 += hv * W2[col * 2 + 1];
                }
                #pragma unroll
                for (int off = 1; off < 16; off <<= 1) {
                    s0 += __shfl_xor(s0, off, 16);
                    s1 += __shfl_xor(s1, off, 16);
                }
                if ((lane & 15) == 0) {
                    int rloc = 16 * fi + (lane >> 4) * 4 + q;
                    plw[wave][rloc][0] = s0;
                    plw[wave][rloc][1] = s1;
                }
            }
        }
        __syncthreads();
        {
            int row = tid >> 1, e = tid & 1;
            float tot = plw[(row >> 6) * 2][row & 63][e] + plw[(row >> 6) * 2 + 1][row & 63][e];
            plog[((size_t)nt * 16384 + m0 + row) * 2 + e] = tot;
        }
    } else {
        if (wn == 0) {
            #pragma unroll
            for (int fi = 0; fi < 4; fi++)
                #pragma unroll
                for (int fj = 0; fj < 3; fj++) {
                    int col = 16 * fj + (lane & 15);
                    if (col < 40) {
                        #pragma unroll
                        for (int q = 0; q < 4; q++) {
                            int row = 64 * wm + 16 * fi + (lane >> 4) * 4 + q;
                            r_raw[(size_t)(m0 + row) * 40 + col] = acc[fi][fj][q];
                        }
                    }
                }
        }
    }
}

// ---------------- gates: sum partial logits, fp32 fixup for near-ties ---------------
__launch_bounds__(256)
__global__ void kgates(const float* __restrict__ plog, const float* __restrict__ b2,
                       const float* __restrict__ x, const float* __restrict__ W1,
                       const float* __restrict__ Cb, const float* __restrict__ W2,
                       float* __restrict__ gates) {
    const int tid = threadIdx.x;
    const int t = blockIdx.x * 256 + tid;
    float l0 = b2[0], l1 = b2[1];
    #pragma unroll
    for (int p = 0; p < 4; p++) {
        l0 += plog[((size_t)p * 16384 + t) * 2];
        l1 += plog[((size_t)p * 16384 + t) * 2 + 1];
    }
    __shared__ int list[256];
    __shared__ float fixv[256][2];
    __shared__ int cnt;
    __shared__ float xrow[1024];
    __shared__ float wred[4][2];
    if (tid == 0) cnt = 0;
    __syncthreads();
    int myi = -1;
    if (fabsf(l0 - l1) < 1e-3f) myi = atomicAdd(&cnt, 1);
    if (myi >= 0) list[myi] = tid;
    __syncthreads();
    const int n = cnt;
    for (int ii = 0; ii < n; ii++) {
        __syncthreads();
        const int lt = list[ii];
        const int tok = blockIdx.x * 256 + lt;
        for (int c = tid; c < 1024; c += 256) xrow[c] = x[(size_t)tok * 1024 + c];
        __syncthreads();
        const int b = tok & 7;
        float pre0 = Cb[b * 512 + tid], pre1 = Cb[b * 512 + tid + 256];
        for (int k = 0; k < 1024; k++) {
            const float xv = xrow[k];
            pre0 += xv * W1[k * 512 + tid];
            pre1 += xv * W1[k * 512 + tid + 256];
        }
        float hv0 = geluf(pre0), hv1 = geluf(pre1);
        float s0 = hv0 * W2[tid * 2] + hv1 * W2[(tid + 256) * 2];
        float s1 = hv0 * W2[tid * 2 + 1] + hv1 * W2[(tid + 256) * 2 + 1];
        #pragma unroll
        for (int off = 1; off < 64; off <<= 1) {
            s0 += __shfl_xor(s0, off, 64);
            s1 += __shfl_xor(s1, off, 64);
        }
        if ((tid & 63) == 0) { wred[tid >> 6][0] = s0; wred[tid >> 6][1] = s1; }
        __syncthreads();
        if (tid == 0) {
            fixv[ii][0] = wred[0][0] + wred[1][0] + wred[2][0] + wred[3][0] + b2[0];
            fixv[ii][1] = wred[0][1] + wred[1][1] + wred[2][1] + wred[3][1] + b2[1];
        }
    }
    __syncthreads();
    if (myi >= 0) { l0 = fixv[myi][0]; l1 = fixv[myi][1]; }
    float topv = 1.f / (1.f + expf(-fabsf(l0 - l1)));
    gates[(size_t)t * 2]     = (l0 >= l1) ? topv : 0.f;
    gates[(size_t)t * 2 + 1] = (l0 >= l1) ? 0.f : topv;
}

// ---------------- delta = (wsc*r)@B_all ; z = bf16(gelu(delta)) ---------------------
__global__ void kdelta(const float* __restrict__ r_raw, const float* __restrict__ gates,
                       const float* __restrict__ actb,
                       const float* __restrict__ B_dyn, const float* __restrict__ B_stat,
                       unsigned short* __restrict__ z) {
    __shared__ float rl[16 * 40];
    const int tid = threadIdx.x;
    const int t0 = blockIdx.x * 16;
    for (int f = tid; f < 640; f += 256) {
        const int tt = t0 + f / 40, j = f % 40, mi = j >> 3;
        float w;
        if (mi == 0) w = gates[(size_t)tt * 2];
        else if (mi == 1) w = gates[(size_t)tt * 2 + 1];
        else if (mi == 2) w = 1.f;
        else w = actb[(tt & 7) * 2 + (mi - 3)];
        rl[f] = w * r_raw[(size_t)tt * 40 + j];
    }
    __syncthreads();
    const int c0 = tid * 4;
    f32x4 acc[16];
    #pragma unroll
    for (int t = 0; t < 16; t++) acc[t] = f32x4{0.f, 0.f, 0.f, 0.f};
    for (int i = 0; i < 40; i++) {
        const float* Brow = (i < 16) ? (B_dyn + (size_t)i * 1024)
                                     : (B_stat + (size_t)(i - 16) * 1024);
        f32x4 b4 = *(const f32x4*)(Brow + c0);
        #pragma unroll
        for (int t = 0; t < 16; t++) acc[t] += b4 * rl[t * 40 + i];
    }
    #pragma unroll
    for (int t = 0; t < 16; t++) {
        f32x4 v = acc[t];
        ushort4 o;
        o.x = f2bf(geluf(v[0])); o.y = f2bf(geluf(v[1]));
        o.z = f2bf(geluf(v[2])); o.w = f2bf(geluf(v[3]));
        *(ushort4*)(z + (size_t)(t0 + t) * 1024 + c0) = o;
    }
}

// ---------------- out = z @ Wout + bout (bf16 MFMA, 128x128 tiles) ------------------
__launch_bounds__(256, 2)
__global__ void kgemm(const unsigned short* __restrict__ z,
                      const unsigned short* __restrict__ WT,
                      const float* __restrict__ bout, float* __restrict__ out) {
    __shared__ unsigned short lA[128 * 32];
    __shared__ unsigned short lB[128 * 32];
    const int tid = threadIdx.x;
    const int lane = tid & 63;
    const int wave = tid >> 6;
    const int m0 = (blockIdx.x >> 3) * 128;
    const int n0 = (blockIdx.x & 7) * 128;
    const int wm = wave >> 1, wn = wave & 1;

    f32x4 acc[4][4];
    #pragma unroll
    for (int i = 0; i < 4; i++)
        #pragma unroll
        for (int j = 0; j < 4; j++) acc[i][j] = f32x4{0.f, 0.f, 0.f, 0.f};

    for (int k0 = 0; k0 < 1024; k0 += 32) {
        __syncthreads();
        #pragma unroll
        for (int q = 0; q < 2; q++) {
            int c = tid + 256 * q;
            int row = c >> 2, ss = c & 3;
            int sl = ss ^ ((row >> 1) & 3);
            f32x4 va = *(const f32x4*)(z + (size_t)(m0 + row) * 1024 + k0 + sl * 8);
            *(f32x4*)&lA[row * 32 + ss * 8] = va;
            f32x4 vb = *(const f32x4*)(WT + (size_t)(n0 + row) * 1024 + k0 + sl * 8);
            *(f32x4*)&lB[row * 32 + ss * 8] = vb;
        }
        __syncthreads();
        bf16x8 af[4], bfr[4];
        #pragma unroll
        for (int fi = 0; fi < 4; fi++) {
            int rA = 64 * wm + 16 * fi + (lane & 15);
            int sl = (lane >> 4) ^ ((rA >> 1) & 3);
            af[fi] = *(const bf16x8*)&lA[rA * 32 + sl * 8];
        }
        #pragma unroll
        for (int fj = 0; fj < 4; fj++) {
            int rB = 64 * wn + 16 * fj + (lane & 15);
            int sl = (lane >> 4) ^ ((rB >> 1) & 3);
            bfr[fj] = *(const bf16x8*)&lB[rB * 32 + sl * 8];
        }
        #pragma unroll
        for (int fi = 0; fi < 4; fi++)
            #pragma unroll
            for (int fj = 0; fj < 4; fj++)
                acc[fi][fj] = __builtin_amdgcn_mfma_f32_16x16x32_bf16(
                    af[fi], bfr[fj], acc[fi][fj], 0, 0, 0);
    }
    #pragma unroll
    for (int fj = 0; fj < 4; fj++) {
        int n = n0 + 64 * wn + 16 * fj + (lane & 15);
        float bo = bout[n];
        #pragma unroll
        for (int fi = 0; fi < 4; fi++) {
            int mr = m0 + 64 * wm + 16 * fi + (lane >> 4) * 4;
            #pragma unroll
            for (int q = 0; q < 4; q++)
                out[(size_t)(mr + q) * 1024 + n] = acc[fi][fj][q] + bo;
        }
    }
}

extern "C" void kernel_launch(void* const* d_in, const int* in_sizes, int n_in,
                              void* d_out, int out_size, void* d_ws, size_t ws_size,
                              hipStream_t stream) {
    const float* x      = (const float*)d_in[0];
    const float* me     = (const float*)d_in[1];
    const float* A_dyn  = (const float*)d_in[2];
    const float* B_dyn  = (const float*)d_in[3];
    const float* W1     = (const float*)d_in[4];
    const float* b1     = (const float*)d_in[5];
    const float* W2     = (const float*)d_in[6];
    const float* b2     = (const float*)d_in[7];
    const float* A_stat = (const float*)d_in[8];
    const float* B_stat = (const float*)d_in[9];
    const float* Wout   = (const float*)d_in[10];
    const float* bout   = (const float*)d_in[11];
    float* out = (float*)d_out;

    char* ws = (char*)d_ws;
    float*          Cb    = (float*)(ws + 0);                 // 16 KB
    float*          actb  = (float*)(ws + 16384);             // 64 B
    unsigned short* WT    = (unsigned short*)(ws + 65536);    // 2 MB
    unsigned short* WThi  = (unsigned short*)(ws + 2162688);  // 1.25 MB
    unsigned short* WTlo  = (unsigned short*)(ws + 3473408);  // 1.25 MB
    float*          plog  = (float*)(ws + 4784128);           // 512 KB
    float*          gates = (float*)(ws + 5308416);           // 128 KB
    float*          r_raw = (float*)(ws + 5439488);           // 2.62 MB
    unsigned short* z     = (unsigned short*)(ws + 8060928);  // 32 MB

    kprep<<<1, 512, 0, stream>>>(me, W1, b1, Cb, actb);
    kwout<<<1024, 256, 0, stream>>>(Wout, WT);
    kwsplit<<<640, 256, 0, stream>>>(W1, A_dyn, A_stat, WThi, WTlo);
    krouterg<<<640, 256, 0, stream>>>(x, WThi, WTlo, Cb, W2, plog, r_raw);
    kgates<<<64, 256, 0, stream>>>(plog, b2, x, W1, Cb, W2, gates);
    kdelta<<<1024, 256, 0, stream>>>(r_raw, gates, actb, B_dyn, B_stat, z);
    kgemm<<<1024, 256, 0, stream>>>(z, WT, bout, out);
}

// Round 3
// 375.309 us; speedup vs baseline: 9.8763x; 1.1104x over previous
//
#include <hip/hip_runtime.h>
#include <hip/hip_bf16.h>

// Shapes (fixed): L=2048, B=8, D=1024, R=8, E=2, RD=8, H=512, NUM_STAT=3, TOPK=1
// tokens M = L*B = 16384
//
// Pipeline:
//  kprep   : Cb[b][512] = b1 + me[b]@W1[1024:], actb flags, fixcnt=0
//  kwout   : WoutT bf16 [n][k]
//  kwsplit : W1cat^T hi/lo bf16 [640][1024] (cols 0-511 = W1, 512-551 = A_all, pad 0)
//  kxbf    : xh = bf16(x)  [16384][1024]
//  krouterg: MFMA GEMM; logit tiles (nt 0-3): xh@(Whi+Wlo) -> gelu -> W2 partials;
//            r tile (nt 4): xh@Whi -> r_raw
//  kgates  : sum plog + b2 -> gates; flag tokens with margin < 8e-3 to fixlist
//  kfix    : exact fp32 logits for flagged tokens (parallel, 1 block/token)
//  kdelta  : rs = wsc*r_raw; delta = rs@B_all; z = bf16(gelu(delta))
//  kgemm   : out = z @ Wout + bout   (bf16 MFMA 128x128 tiles)

typedef __attribute__((ext_vector_type(4))) float f32x4;
typedef __attribute__((ext_vector_type(8))) short bf16x8;
typedef __attribute__((ext_vector_type(8))) unsigned short u16x8;

__device__ __forceinline__ float geluf(float v) {
    return 0.5f * v * (1.0f + erff(v * 0.70710678118654752440f));
}
__device__ __forceinline__ unsigned short f2bf(float v) {
    return __builtin_bit_cast(unsigned short, __float2bfloat16(v));
}
__device__ __forceinline__ float bf2f(unsigned short u) {
    unsigned int x = ((unsigned int)u) << 16;
    return __builtin_bit_cast(float, x);
}
__device__ __forceinline__ void gload16(const void* g, void* l) {
    __builtin_amdgcn_global_load_lds(
        (const __attribute__((address_space(1))) unsigned int*)g,
        (__attribute__((address_space(3))) unsigned int*)l, 16, 0, 0);
}

// ---------------- prep ---------------------------------------------------------------
__global__ void kprep(const float* __restrict__ me, const float* __restrict__ W1,
                      const float* __restrict__ b1, float* __restrict__ Cb,
                      float* __restrict__ actb, int* __restrict__ fixcnt) {
    int h = threadIdx.x;  // 512 threads
    for (int b = 0; b < 8; b++) {
        float s = b1[h];
        #pragma unroll
        for (int r = 0; r < 8; r++) s += me[b * 8 + r] * W1[(1024 + r) * 512 + h];
        Cb[b * 512 + h] = s;
    }
    if (h < 16) {
        int b = h >> 1, j = h & 1;
        actb[b * 2 + j] = (me[b * 8 + 1 + j] > 0.5f) ? 1.0f : 0.0f;
    }
    if (h == 0) *fixcnt = 0;
}

// ---------------- Wout -> WoutT (bf16, [n][k]) ---------------------------------------
__global__ void kwout(const float* __restrict__ Wout, unsigned short* __restrict__ WT) {
    __shared__ float s[32][33];
    const int blk = blockIdx.x;
    const int kt = blk >> 5, nt = blk & 31;
    const int r = threadIdx.x >> 3, c4 = (threadIdx.x & 7) * 4;
    f32x4 v = *(const f32x4*)(Wout + (size_t)(kt * 32 + r) * 1024 + nt * 32 + c4);
    s[r][c4 + 0] = v[0]; s[r][c4 + 1] = v[1]; s[r][c4 + 2] = v[2]; s[r][c4 + 3] = v[3];
    __syncthreads();
    const int n = r, kc = c4;
    ushort4 o;
    o.x = f2bf(s[kc + 0][n]); o.y = f2bf(s[kc + 1][n]);
    o.z = f2bf(s[kc + 2][n]); o.w = f2bf(s[kc + 3][n]);
    *(ushort4*)(WT + (size_t)(nt * 32 + n) * 1024 + kt * 32 + kc) = o;
}

// ---------------- build W1cat^T hi/lo: [640][1024] bf16 each -------------------------
__global__ void kwsplit(const float* __restrict__ W1, const float* __restrict__ A_dyn,
                        const float* __restrict__ A_stat,
                        unsigned short* __restrict__ WThi, unsigned short* __restrict__ WTlo) {
    __shared__ float s[32][33];
    const int nt = blockIdx.x >> 5;   // 0..19
    const int kt = blockIdx.x & 31;   // 0..31
    const int r = threadIdx.x >> 3;
    const int c4 = (threadIdx.x & 7) * 4;
    const int k = kt * 32 + r;
    if (nt < 16) {
        f32x4 v = *(const f32x4*)(W1 + (size_t)k * 512 + nt * 32 + c4);
        s[r][c4 + 0] = v[0]; s[r][c4 + 1] = v[1];
        s[r][c4 + 2] = v[2]; s[r][c4 + 3] = v[3];
    } else {
        #pragma unroll
        for (int j = 0; j < 4; j++) {
            int ng = nt * 32 + c4 + j;
            float val = 0.f;
            if (ng < 552) {
                int mi = (ng - 512) >> 3, rr = (ng - 512) & 7;
                const float* Ab = (mi < 2) ? (A_dyn + (size_t)mi * 8192)
                                           : (A_stat + (size_t)(mi - 2) * 8192);
                val = Ab[(size_t)k * 8 + rr];
            }
            s[r][c4 + j] = val;
        }
    }
    __syncthreads();
    ushort4 oh, ol;
    float f0 = s[c4 + 0][r], f1 = s[c4 + 1][r], f2 = s[c4 + 2][r], f3 = s[c4 + 3][r];
    oh.x = f2bf(f0); ol.x = f2bf(f0 - bf2f(oh.x));
    oh.y = f2bf(f1); ol.y = f2bf(f1 - bf2f(oh.y));
    oh.z = f2bf(f2); ol.z = f2bf(f2 - bf2f(oh.z));
    oh.w = f2bf(f3); ol.w = f2bf(f3 - bf2f(oh.w));
    size_t obase = (size_t)(nt * 32 + r) * 1024 + kt * 32 + c4;
    *(ushort4*)(WThi + obase) = oh;
    *(ushort4*)(WTlo + obase) = ol;
}

// ---------------- x -> bf16 ----------------------------------------------------------
__global__ void kxbf(const float* __restrict__ x, unsigned short* __restrict__ xh) {
    const size_t i = ((size_t)blockIdx.x * 256 + threadIdx.x) * 8;
    f32x4 a = *(const f32x4*)(x + i);
    f32x4 b = *(const f32x4*)(x + i + 4);
    u16x8 o;
    o[0] = f2bf(a[0]); o[1] = f2bf(a[1]); o[2] = f2bf(a[2]); o[3] = f2bf(a[3]);
    o[4] = f2bf(b[0]); o[5] = f2bf(b[1]); o[6] = f2bf(b[2]); o[7] = f2bf(b[3]);
    *(u16x8*)(xh + i) = o;
}

// ---------------- router GEMM --------------------------------------------------------
__launch_bounds__(256)
__global__ void krouterg(const unsigned short* __restrict__ xh,
                         const unsigned short* __restrict__ WThi,
                         const unsigned short* __restrict__ WTlo,
                         const float* __restrict__ Cb,
                         const float* __restrict__ W2,
                         float* __restrict__ plog,
                         float* __restrict__ r_raw) {
    __shared__ unsigned short xs[128 * 32], bhs[128 * 32], bls[128 * 32];
    __shared__ float plw[4][64][2];

    const int tid = threadIdx.x;
    const int lane = tid & 63;
    const int wave = tid >> 6;
    const int nt = blockIdx.x % 5;
    const int mb = blockIdx.x / 5;
    const int m0 = mb * 128, n0 = nt * 128;
    const int wm = wave >> 1, wn = wave & 1;
    const bool rtile = (nt == 4);

    f32x4 acc[4][4];
    #pragma unroll
    for (int i = 0; i < 4; i++)
        #pragma unroll
        for (int j = 0; j < 4; j++) acc[i][j] = f32x4{0.f, 0.f, 0.f, 0.f};

    // staging map: 2 chunks of 16B per thread per tile; linear LDS dest,
    // pre-swizzled global source (involution XOR on 16B slot within 64B row)
    int srow[2], ssl[2], sofs[2];
    #pragma unroll
    for (int i = 0; i < 2; i++) {
        int ldsbyte = i * 4096 + tid * 16;
        int row = ldsbyte >> 6;
        int ss = (ldsbyte >> 4) & 3;
        srow[i] = row;
        ssl[i] = ss ^ ((row >> 1) & 3);
        sofs[i] = ldsbyte >> 1;
    }

    // fragment LDS offsets (swizzled read)
    int aoff[4], boff[4];
    #pragma unroll
    for (int f = 0; f < 4; f++) {
        int rA = 64 * wm + 16 * f + (lane & 15);
        aoff[f] = rA * 32 + (((lane >> 4) ^ ((rA >> 1) & 3)) * 8);
        int rB = 64 * wn + 16 * f + (lane & 15);
        boff[f] = rB * 32 + (((lane >> 4) ^ ((rB >> 1) & 3)) * 8);
    }

    const unsigned short* xb = xh + (size_t)m0 * 1024;
    const unsigned short* bhb = WThi + (size_t)n0 * 1024;
    const unsigned short* blb = WTlo + (size_t)n0 * 1024;

    for (int k0 = 0; k0 < 1024; k0 += 32) {
        __syncthreads();
        #pragma unroll
        for (int i = 0; i < 2; i++) {
            const size_t go = (size_t)srow[i] * 1024 + k0 + ssl[i] * 8;
            gload16(xb + go, &xs[sofs[i]]);
            gload16(bhb + go, &bhs[sofs[i]]);
            if (!rtile) gload16(blb + go, &bls[sofs[i]]);
        }
        __syncthreads();
        bf16x8 ah[4], bh[4];
        #pragma unroll
        for (int f = 0; f < 4; f++) {
            ah[f] = *(const bf16x8*)&xs[aoff[f]];
            bh[f] = *(const bf16x8*)&bhs[boff[f]];
        }
        if (!rtile) {
            bf16x8 bl[4];
            #pragma unroll
            for (int f = 0; f < 4; f++) bl[f] = *(const bf16x8*)&bls[boff[f]];
            #pragma unroll
            for (int fi = 0; fi < 4; fi++)
                #pragma unroll
                for (int fj = 0; fj < 4; fj++) {
                    acc[fi][fj] = __builtin_amdgcn_mfma_f32_16x16x32_bf16(ah[fi], bh[fj], acc[fi][fj], 0, 0, 0);
                    acc[fi][fj] = __builtin_amdgcn_mfma_f32_16x16x32_bf16(ah[fi], bl[fj], acc[fi][fj], 0, 0, 0);
                }
        } else if (wn == 0) {
            #pragma unroll
            for (int fi = 0; fi < 4; fi++)
                #pragma unroll
                for (int fj = 0; fj < 3; fj++)
                    acc[fi][fj] = __builtin_amdgcn_mfma_f32_16x16x32_bf16(ah[fi], bh[fj], acc[fi][fj], 0, 0, 0);
        }
    }

    if (!rtile) {
        // partial logits over this block's 128 h-cols
        #pragma unroll
        for (int fi = 0; fi < 4; fi++) {
            #pragma unroll
            for (int q = 0; q < 4; q++) {
                const int b = (((lane >> 4) * 4 + q) & 7);
                float s0 = 0.f, s1 = 0.f;
                #pragma unroll
                for (int fj = 0; fj < 4; fj++) {
                    int col = n0 + 64 * wn + 16 * fj + (lane & 15);
                    float val = acc[fi][fj][q] + Cb[b * 512 + col];
                    float hv = geluf(val);
                    s0 += hv * W2[col * 2];
                    s1 += hv * W2[col * 2 + 1];
                }
                #pragma unroll
                for (int off = 1; off < 16; off <<= 1) {
                    s0 += __shfl_xor(s0, off, 16);
                    s1 += __shfl_xor(s1, off, 16);
                }
                if ((lane & 15) == 0) {
                    int rloc = 16 * fi + (lane >> 4) * 4 + q;
                    plw[wave][rloc][0] = s0;
                    plw[wave][rloc][1] = s1;
                }
            }
        }
        __syncthreads();
        {
            int row = tid >> 1, e = tid & 1;
            float tot = plw[(row >> 6) * 2][row & 63][e] + plw[(row >> 6) * 2 + 1][row & 63][e];
            plog[((size_t)nt * 16384 + m0 + row) * 2 + e] = tot;
        }
    } else {
        if (wn == 0) {
            #pragma unroll
            for (int fi = 0; fi < 4; fi++)
                #pragma unroll
                for (int fj = 0; fj < 3; fj++) {
                    int col = 16 * fj + (lane & 15);
                    if (col < 40) {
                        #pragma unroll
                        for (int q = 0; q < 4; q++) {
                            int row = 64 * wm + 16 * fi + (lane >> 4) * 4 + q;
                            r_raw[(size_t)(m0 + row) * 40 + col] = acc[fi][fj][q];
                        }
                    }
                }
        }
    }
}

// ---------------- gates + flag near-ties ---------------------------------------------
__global__ void kgates(const float* __restrict__ plog, const float* __restrict__ b2,
                       float* __restrict__ gates, int* __restrict__ fixlist,
                       int* __restrict__ fixcnt) {
    const int t = blockIdx.x * 256 + threadIdx.x;
    float l0 = b2[0], l1 = b2[1];
    #pragma unroll
    for (int p = 0; p < 4; p++) {
        l0 += plog[((size_t)p * 16384 + t) * 2];
        l1 += plog[((size_t)p * 16384 + t) * 2 + 1];
    }
    if (fabsf(l0 - l1) < 8e-3f) {
        int i = atomicAdd(fixcnt, 1);
        fixlist[i] = t;
    }
    float topv = 1.f / (1.f + expf(-fabsf(l0 - l1)));
    gates[(size_t)t * 2]     = (l0 >= l1) ? topv : 0.f;
    gates[(size_t)t * 2 + 1] = (l0 >= l1) ? 0.f : topv;
}

// ---------------- exact fp32 fixup, one block per flagged token ----------------------
__launch_bounds__(256)
__global__ void kfix(const int* __restrict__ fixlist, const int* __restrict__ fixcnt,
                     const float* __restrict__ x, const float* __restrict__ W1,
                     const float* __restrict__ Cb, const float* __restrict__ W2,
                     const float* __restrict__ b2, float* __restrict__ gates) {
    __shared__ float xrow[1024];
    __shared__ float wred[4][2];
    const int tid = threadIdx.x;
    const int n = *fixcnt;
    for (int i = blockIdx.x; i < n; i += gridDim.x) {
        const int tok = fixlist[i];
        __syncthreads();
        for (int c = tid; c < 1024; c += 256) xrow[c] = x[(size_t)tok * 1024 + c];
        __syncthreads();
        const int b = tok & 7;
        float pre0 = Cb[b * 512 + tid], pre1 = Cb[b * 512 + tid + 256];
        for (int k = 0; k < 1024; k++) {
            const float xv = xrow[k];
            pre0 += xv * W1[k * 512 + tid];
            pre1 += xv * W1[k * 512 + tid + 256];
        }
        float h0 = geluf(pre0), h1 = geluf(pre1);
        float s0 = h0 * W2[tid * 2] + h1 * W2[(tid + 256) * 2];
        float s1 = h0 * W2[tid * 2 + 1] + h1 * W2[(tid + 256) * 2 + 1];
        #pragma unroll
        for (int off = 1; off < 64; off <<= 1) {
            s0 += __shfl_xor(s0, off, 64);
            s1 += __shfl_xor(s1, off, 64);
        }
        if ((tid & 63) == 0) { wred[tid >> 6][0] = s0; wred[tid >> 6][1] = s1; }
        __syncthreads();
        if (tid == 0) {
            float l0 = wred[0][0] + wred[1][0] + wred[2][0] + wred[3][0] + b2[0];
            float l1 = wred[0][1] + wred[1][1] + wred[2][1] + wred[3][1] + b2[1];
            float topv = 1.f / (1.f + expf(-fabsf(l0 - l1)));
            gates[(size_t)tok * 2]     = (l0 >= l1) ? topv : 0.f;
            gates[(size_t)tok * 2 + 1] = (l0 >= l1) ? 0.f : topv;
        }
        __syncthreads();
    }
}

// ---------------- delta = (wsc*r)@B_all ; z = bf16(gelu(delta)) ----------------------
__global__ void kdelta(const float* __restrict__ r_raw, const float* __restrict__ gates,
                       const float* __restrict__ actb,
                       const float* __restrict__ B_dyn, const float* __restrict__ B_stat,
                       unsigned short* __restrict__ z) {
    __shared__ float rl[16 * 40];
    const int tid = threadIdx.x;
    const int t0 = blockIdx.x * 16;
    for (int f = tid; f < 640; f += 256) {
        const int tt = t0 + f / 40, j = f % 40, mi = j >> 3;
        float w;
        if (mi == 0) w = gates[(size_t)tt * 2];
        else if (mi == 1) w = gates[(size_t)tt * 2 + 1];
        else if (mi == 2) w = 1.f;
        else w = actb[(tt & 7) * 2 + (mi - 3)];
        rl[f] = w * r_raw[(size_t)tt * 40 + j];
    }
    __syncthreads();
    const int c0 = tid * 4;
    f32x4 acc[16];
    #pragma unroll
    for (int t = 0; t < 16; t++) acc[t] = f32x4{0.f, 0.f, 0.f, 0.f};
    for (int i = 0; i < 40; i++) {
        const float* Brow = (i < 16) ? (B_dyn + (size_t)i * 1024)
                                     : (B_stat + (size_t)(i - 16) * 1024);
        f32x4 b4 = *(const f32x4*)(Brow + c0);
        #pragma unroll
        for (int t = 0; t < 16; t++) acc[t] += b4 * rl[t * 40 + i];
    }
    #pragma unroll
    for (int t = 0; t < 16; t++) {
        f32x4 v = acc[t];
        ushort4 o;
        o.x = f2bf(geluf(v[0])); o.y = f2bf(geluf(v[1]));
        o.z = f2bf(geluf(v[2])); o.w = f2bf(geluf(v[3]));
        *(ushort4*)(z + (size_t)(t0 + t) * 1024 + c0) = o;
    }
}

// ---------------- out = z @ Wout + bout (bf16 MFMA, 128x128 tiles) -------------------
__launch_bounds__(256, 2)
__global__ void kgemm(const unsigned short* __restrict__ z,
                      const unsigned short* __restrict__ WT,
                      const float* __restrict__ bout, float* __restrict__ out) {
    __shared__ unsigned short lA[128 * 32];
    __shared__ unsigned short lB[128 * 32];
    const int tid = threadIdx.x;
    const int lane = tid & 63;
    const int wave = tid >> 6;
    const int m0 = (blockIdx.x >> 3) * 128;
    const int n0 = (blockIdx.x & 7) * 128;
    const int wm = wave >> 1, wn = wave & 1;

    f32x4 acc[4][4];
    #pragma unroll
    for (int i = 0; i < 4; i++)
        #pragma unroll
        for (int j = 0; j < 4; j++) acc[i][j] = f32x4{0.f, 0.f, 0.f, 0.f};

    for (int k0 = 0; k0 < 1024; k0 += 32) {
        __syncthreads();
        #pragma unroll
        for (int q = 0; q < 2; q++) {
            int c = tid + 256 * q;
            int row = c >> 2, ss = c & 3;
            int sl = ss ^ ((row >> 1) & 3);
            f32x4 va = *(const f32x4*)(z + (size_t)(m0 + row) * 1024 + k0 + sl * 8);
            *(f32x4*)&lA[row * 32 + ss * 8] = va;
            f32x4 vb = *(const f32x4*)(WT + (size_t)(n0 + row) * 1024 + k0 + sl * 8);
            *(f32x4*)&lB[row * 32 + ss * 8] = vb;
        }
        __syncthreads();
        bf16x8 af[4], bfr[4];
        #pragma unroll
        for (int fi = 0; fi < 4; fi++) {
            int rA = 64 * wm + 16 * fi + (lane & 15);
            int sl = (lane >> 4) ^ ((rA >> 1) & 3);
            af[fi] = *(const bf16x8*)&lA[rA * 32 + sl * 8];
        }
        #pragma unroll
        for (int fj = 0; fj < 4; fj++) {
            int rB = 64 * wn + 16 * fj + (lane & 15);
            int sl = (lane >> 4) ^ ((rB >> 1) & 3);
            bfr[fj] = *(const bf16x8*)&lB[rB * 32 + sl * 8];
        }
        #pragma unroll
        for (int fi = 0; fi < 4; fi++)
            #pragma unroll
            for (int fj = 0; fj < 4; fj++)
                acc[fi][fj] = __builtin_amdgcn_mfma_f32_16x16x32_bf16(
                    af[fi], bfr[fj], acc[fi][fj], 0, 0, 0);
    }
    #pragma unroll
    for (int fj = 0; fj < 4; fj++) {
        int n = n0 + 64 * wn + 16 * fj + (lane & 15);
        float bo = bout[n];
        #pragma unroll
        for (int fi = 0; fi < 4; fi++) {
            int mr = m0 + 64 * wm + 16 * fi + (lane >> 4) * 4;
            #pragma unroll
            for (int q = 0; q < 4; q++)
                out[(size_t)(mr + q) * 1024 + n] = acc[fi][fj][q] + bo;
        }
    }
}

extern "C" void kernel_launch(void* const* d_in, const int* in_sizes, int n_in,
                              void* d_out, int out_size, void* d_ws, size_t ws_size,
                              hipStream_t stream) {
    const float* x      = (const float*)d_in[0];
    const float* me     = (const float*)d_in[1];
    const float* A_dyn  = (const float*)d_in[2];
    const float* B_dyn  = (const float*)d_in[3];
    const float* W1     = (const float*)d_in[4];
    const float* b1     = (const float*)d_in[5];
    const float* W2     = (const float*)d_in[6];
    const float* b2     = (const float*)d_in[7];
    const float* A_stat = (const float*)d_in[8];
    const float* B_stat = (const float*)d_in[9];
    const float* Wout   = (const float*)d_in[10];
    const float* bout   = (const float*)d_in[11];
    float* out = (float*)d_out;

    char* ws = (char*)d_ws;
    float*          Cb     = (float*)(ws + 0);                 // 16 KB
    float*          actb   = (float*)(ws + 16384);             // 64 B
    int*            fixcnt = (int*)(ws + 16448);               // 4 B
    unsigned short* WT     = (unsigned short*)(ws + 65536);    // 2 MB
    unsigned short* WThi   = (unsigned short*)(ws + 2162688);  // 1.31 MB
    unsigned short* WTlo   = (unsigned short*)(ws + 3473408);  // 1.31 MB
    float*          plog   = (float*)(ws + 4784128);           // 512 KB
    float*          gates  = (float*)(ws + 5308416);           // 128 KB
    float*          r_raw  = (float*)(ws + 5439488);           // 2.62 MB
    int*            fixlist= (int*)(ws + 8060928);             // 64 KB
    unsigned short* xh     = (unsigned short*)(ws + 8126464);  // 32 MB
    unsigned short* z      = (unsigned short*)(ws + 41680896); // 32 MB

    kprep<<<1, 512, 0, stream>>>(me, W1, b1, Cb, actb, fixcnt);
    kwout<<<1024, 256, 0, stream>>>(Wout, WT);
    kwsplit<<<640, 256, 0, stream>>>(W1, A_dyn, A_stat, WThi, WTlo);
    kxbf<<<8192, 256, 0, stream>>>(x, xh);
    krouterg<<<640, 256, 0, stream>>>(xh, WThi, WTlo, Cb, W2, plog, r_raw);
    kgates<<<64, 256, 0, stream>>>(plog, b2, gates, fixlist, fixcnt);
    kfix<<<128, 256, 0, stream>>>(fixlist, fixcnt, x, W1, Cb, W2, b2, gates);
    kdelta<<<1024, 256, 0, stream>>>(r_raw, gates, actb, B_dyn, B_stat, z);
    kgemm<<<1024, 256, 0, stream>>>(z, WT, bout, out);
}